// Round 7
// baseline (459.884 us; speedup 1.0000x reference)
//
#include <hip/hip_runtime.h>
#include <hip/hip_bf16.h>

// GCN on MI355X. Pipeline:
//   CSR-by-dst via two-level bucket binning
//   edge_weights     : pay2[i] = {col, dinv[col]}
//   gemm128<fp32 A>  : x @ W1 -> bufA (bf16, row-major 256B rows)
//   aggregate_slice  : XCD-sliced gather-sum + bias + relu -> bufB (bf16)
//   gemm128<bf16 A>  : bufB @ W2 -> bufA (bf16)
//   aggregate_slice  : -> bufC (a2, bf16)
//   gemm_out16       : a2 @ Wc + bc -> out (fp32)
// Aggregate slicing: grid = 4 x node-blocks, slice = blockIdx & 3. A slice
// is the s-th 64B LINE of each 256B row -> slice working set 3.2MB fits one
// XCD 4MB L2; with round-robin blockIdx->XCD, slice s pins to XCDs {s,s+4}.
// Gather: 16 groups x 4 lanes, uint4/lane = 16 edges per load instruction.
// pay2 nt-loaded, outputs nt-stored (don't evict the L2-resident slice).
// h bf16; accumulation fp32. Requires n <= 65536.

typedef unsigned int uint;
typedef unsigned long long ull;

#define NPB 256
#define MAXBKT 256

static __device__ __forceinline__ unsigned short f2bf(float f) {
    unsigned u = __float_as_uint(f);
    u += 0x7fffu + ((u >> 16) & 1u);   // round-to-nearest-even
    return (unsigned short)(u >> 16);
}
static __device__ __forceinline__ uint pack2(float a, float b) {
    return (uint)f2bf(a) | ((uint)f2bf(b) << 16);
}
static __device__ __forceinline__ float lo2f(uint u) { return __uint_as_float(u << 16); }
static __device__ __forceinline__ float hi2f(uint u) { return __uint_as_float(u & 0xffff0000u); }

#define UNPACK8(dst, u)                                        \
    dst[0] = lo2f(u.x); dst[1] = hi2f(u.x);                    \
    dst[2] = lo2f(u.y); dst[3] = hi2f(u.y);                    \
    dst[4] = lo2f(u.z); dst[5] = hi2f(u.z);                    \
    dst[6] = lo2f(u.w); dst[7] = hi2f(u.w);

// ---------------- CSR build (bucketed) ----------------

__global__ __launch_bounds__(256) void bucket_hist(const int* __restrict__ dst,
                                                   int* __restrict__ bcount,
                                                   int E, int nbuckets) {
    __shared__ int h[MAXBKT];
    int tid = threadIdx.x;
    h[tid] = 0;
    __syncthreads();
    int chunk = (E + gridDim.x - 1) / gridDim.x;
    int i0 = blockIdx.x * chunk;
    int i1 = min(E, i0 + chunk);
    for (int i = i0 + tid; i < i1; i += 256) atomicAdd(&h[dst[i] >> 8], 1);
    __syncthreads();
    if (tid < nbuckets && h[tid]) atomicAdd(&bcount[tid], h[tid]);
}

__global__ __launch_bounds__(256) void scan196(const int* __restrict__ bcount,
                                               int* __restrict__ bbase,
                                               int* __restrict__ bcursor,
                                               int nbuckets, int E) {
    __shared__ int s[MAXBKT];
    int t = threadIdx.x;
    int v = (t < nbuckets) ? bcount[t] : 0;
    s[t] = v;
    __syncthreads();
    for (int d = 1; d < 256; d <<= 1) {
        int x = (t >= d) ? s[t - d] : 0;
        __syncthreads();
        s[t] += x;
        __syncthreads();
    }
    if (t < nbuckets) {
        int ex = s[t] - v;
        bbase[t] = ex;
        bcursor[t] = ex;
    }
    if (t == 0) bbase[nbuckets] = E;
}

__global__ __launch_bounds__(256) void bin_edges(const int* __restrict__ src,
                                                 const int* __restrict__ dst,
                                                 int* __restrict__ bcursor,
                                                 uint* __restrict__ pay,
                                                 int E, int nbuckets) {
    __shared__ int h[MAXBKT];
    __shared__ int base[MAXBKT];
    int tid = threadIdx.x;
    h[tid] = 0;
    __syncthreads();
    int chunk = (E + gridDim.x - 1) / gridDim.x;
    int i0 = blockIdx.x * chunk;
    int i1 = min(E, i0 + chunk);
    for (int i = i0 + tid; i < i1; i += 256) atomicAdd(&h[dst[i] >> 8], 1);
    __syncthreads();
    if (tid < nbuckets) base[tid] = h[tid] ? atomicAdd(&bcursor[tid], h[tid]) : 0;
    __syncthreads();
    h[tid] = 0;
    __syncthreads();
    for (int i = i0 + tid; i < i1; i += 256) {
        int d = dst[i];
        int b = d >> 8;
        int pos = base[b] + atomicAdd(&h[b], 1);
        pay[pos] = (uint)src[i] | ((uint)(d & 255) << 24);
    }
}

__global__ __launch_bounds__(256) void build_rows(const uint* __restrict__ pay,
                                                  const int* __restrict__ bbase,
                                                  int* __restrict__ rowstart,
                                                  float* __restrict__ dinv,
                                                  int* __restrict__ colidx,
                                                  int n, int E, int nbuckets) {
    __shared__ int hist[NPB];
    __shared__ int sc[NPB];
    __shared__ int cur[NPB];
    int tid = threadIdx.x;
    int b = blockIdx.x;
    int node0 = b * NPB;
    int s = bbase[b], e = bbase[b + 1];

    hist[tid] = 0;
    __syncthreads();
    for (int i = s + tid; i < e; i += 256) atomicAdd(&hist[pay[i] >> 24], 1);
    __syncthreads();

    int v = hist[tid];
    sc[tid] = v;
    __syncthreads();
    for (int d = 1; d < 256; d <<= 1) {
        int x = (tid >= d) ? sc[tid - d] : 0;
        __syncthreads();
        sc[tid] += x;
        __syncthreads();
    }
    int excl = sc[tid] - v;
    cur[tid] = s + excl;
    int node = node0 + tid;
    if (node < n) {
        rowstart[node] = s + excl;
        dinv[node] = rsqrtf((float)(v + 1));  // +1 self-loop
    }
    if (b == nbuckets - 1 && tid == 0) rowstart[n] = E;
    __syncthreads();

    for (int i = s + tid; i < e; i += 256) {
        uint p = pay[i];
        int pos = atomicAdd(&cur[p >> 24], 1);
        colidx[pos] = (int)(p & 0xffffffu);
    }
}

// pay2[i] = {col, dinv[col]} packed in 8B
__global__ __launch_bounds__(256) void edge_weights(const int* __restrict__ colidx,
                                                    const float* __restrict__ dinv,
                                                    ull* __restrict__ pay2, int E) {
    int i = blockIdx.x * 256 + threadIdx.x;
    if (i < E) {
        int c = colidx[i];
        pay2[i] = (ull)(uint)c | ((ull)(uint)__float_as_uint(dinv[c]) << 32);
    }
}

// ---------------- GEMM n x 128 @ 128 x 128, bf16 packed output ----------------
template <bool A_BF16>
__global__ __launch_bounds__(256) void gemm128(const void* __restrict__ Xv,
                                               const float* __restrict__ W,
                                               uint* __restrict__ Yb, int n) {
    __shared__ float sW[32 * 128];  // 16 KB
    const int tid = threadIdx.x;
    const int row0 = blockIdx.x * 64;
    const int ty = tid >> 4, tx = tid & 15;
    const int c0 = tx * 4;
    int r[4];
#pragma unroll
    for (int i = 0; i < 4; ++i) {
        int rr = row0 + ty * 4 + i;
        r[i] = rr < n ? rr : n - 1;
    }

    float acc[4][8];
#pragma unroll
    for (int i = 0; i < 4; ++i)
#pragma unroll
        for (int j = 0; j < 8; ++j) acc[i][j] = 0.f;

    for (int kc = 0; kc < 128; kc += 32) {
        __syncthreads();
        {
            const float4* W4 = (const float4*)(W + kc * 128);
            float4* s4 = (float4*)sW;
#pragma unroll
            for (int i = 0; i < 4; ++i) s4[tid + 256 * i] = W4[tid + 256 * i];
        }
        __syncthreads();

        for (int k4 = 0; k4 < 32; k4 += 4) {
            float a[4][4];
            if (A_BF16) {
                const uint2* X2 = (const uint2*)Xv;
#pragma unroll
                for (int i = 0; i < 4; ++i) {
                    uint2 u = X2[(size_t)r[i] * 32 + ((kc + k4) >> 2)];
                    a[i][0] = lo2f(u.x); a[i][1] = hi2f(u.x);
                    a[i][2] = lo2f(u.y); a[i][3] = hi2f(u.y);
                }
            } else {
                const float4* X4 = (const float4*)Xv;
#pragma unroll
                for (int i = 0; i < 4; ++i) {
                    float4 vv = X4[(size_t)r[i] * 32 + ((kc + k4) >> 2)];
                    a[i][0] = vv.x; a[i][1] = vv.y; a[i][2] = vv.z; a[i][3] = vv.w;
                }
            }
#pragma unroll
            for (int kk = 0; kk < 4; ++kk) {
                const int k = k4 + kk;
                float4 w0 = *(const float4*)&sW[k * 128 + c0];
                float4 w1 = *(const float4*)&sW[k * 128 + 64 + c0];
                float wv[8] = {w0.x, w0.y, w0.z, w0.w, w1.x, w1.y, w1.z, w1.w};
#pragma unroll
                for (int i = 0; i < 4; ++i) {
                    float av = a[i][kk];
#pragma unroll
                    for (int j = 0; j < 8; ++j) acc[i][j] = fmaf(av, wv[j], acc[i][j]);
                }
            }
        }
    }

#pragma unroll
    for (int i = 0; i < 4; ++i) {
        int rr = row0 + ty * 4 + i;
        if (rr < n) {
            uint2 o0 = {pack2(acc[i][0], acc[i][1]), pack2(acc[i][2], acc[i][3])};
            uint2 o1 = {pack2(acc[i][4], acc[i][5]), pack2(acc[i][6], acc[i][7])};
            *(uint2*)&Yb[(size_t)rr * 64 + (c0 >> 1)] = o0;
            *(uint2*)&Yb[(size_t)rr * 64 + 32 + (c0 >> 1)] = o1;
        }
    }
}

// ---------------- sliced aggregate ----------------
// 16 groups x 4 lanes; group g gathers edge base+g's 64B slice (uint4/lane).
// acc[8] = cols slice*32 + sub*8 .. +8; complete after xor-reduce over groups.
static __device__ __forceinline__ void gather_slice(const uint4* __restrict__ H4,
                                                    const int* __restrict__ rowstart,
                                                    const ull* __restrict__ pay2,
                                                    int wid, int soff /*slice*4+sub*/,
                                                    int g, float di, float acc[8]) {
    uint4 su = H4[(size_t)wid * 16 + soff];
    float t[8];
    UNPACK8(t, su);
    float wS = (g == 0) ? di : 0.f;   // self-loop counted once
#pragma unroll
    for (int j = 0; j < 8; ++j) acc[j] = wS * t[j];

    int s = rowstart[wid], e = rowstart[wid + 1];
    for (int base = s; base < e; base += 16) {
        int p = base + g;
        ull ev = __builtin_nontemporal_load(&pay2[p < e ? p : e - 1]);
        int c = (p < e) ? (int)(uint)ev : wid;              // dummy -> self (L1-hot)
        float w = (p < e) ? __uint_as_float((uint)(ev >> 32)) : 0.f;
        uint4 u = H4[(size_t)c * 16 + soff];
        float a[8];
        UNPACK8(a, u);
#pragma unroll
        for (int j = 0; j < 8; ++j) acc[j] = fmaf(w, a[j], acc[j]);
    }
#pragma unroll
    for (int m = 4; m < 64; m <<= 1) {
#pragma unroll
        for (int j = 0; j < 8; ++j) acc[j] += __shfl_xor(acc[j], m, 64);
    }
}

// out[i, slice cols] = relu( dinv_i*(gather) + b ), bf16, nt-stored.
__global__ __launch_bounds__(256) void aggregate_slice(const uint* __restrict__ Hb,
                                                       const int* __restrict__ rowstart,
                                                       const ull* __restrict__ pay2,
                                                       const float* __restrict__ dinv,
                                                       const float* __restrict__ bias,
                                                       uint* __restrict__ Ob, int n) {
    int b = blockIdx.x;
    int slice = b & 3;
    int wid = (b >> 2) * 4 + (threadIdx.x >> 6);
    if (wid >= n) return;
    int lane = threadIdx.x & 63;
    int g = lane >> 2, sub = lane & 3;
    int soff = slice * 4 + sub;

    float di = dinv[wid];
    float acc[8];
    gather_slice((const uint4*)Hb, rowstart, pay2, wid, soff, g, di, acc);

    if (g == 0) {
        int cb = slice * 8 + sub * 2;  // float4 index into bias
        float4 b0 = ((const float4*)bias)[cb];
        float4 b1 = ((const float4*)bias)[cb + 1];
        float o0 = fmaxf(fmaf(acc[0], di, b0.x), 0.f);
        float o1 = fmaxf(fmaf(acc[1], di, b0.y), 0.f);
        float o2 = fmaxf(fmaf(acc[2], di, b0.z), 0.f);
        float o3 = fmaxf(fmaf(acc[3], di, b0.w), 0.f);
        float o4 = fmaxf(fmaf(acc[4], di, b1.x), 0.f);
        float o5 = fmaxf(fmaf(acc[5], di, b1.y), 0.f);
        float o6 = fmaxf(fmaf(acc[6], di, b1.z), 0.f);
        float o7 = fmaxf(fmaf(acc[7], di, b1.w), 0.f);
        ull lo = (ull)pack2(o0, o1) | ((ull)pack2(o2, o3) << 32);
        ull hi = (ull)pack2(o4, o5) | ((ull)pack2(o6, o7) << 32);
        ull* dst = (ull*)Ob + ((size_t)wid * 16 + soff) * 2;
        __builtin_nontemporal_store(lo, dst);
        __builtin_nontemporal_store(hi, dst + 1);
    }
}

// ---------------- final GEMM n x 128 (bf16) @ 128 x 16 + bias ----------------
__global__ __launch_bounds__(256) void gemm_out16(const uint* __restrict__ Hb,
                                                  const float* __restrict__ Wc,
                                                  const float* __restrict__ bc,
                                                  float* __restrict__ out, int n) {
    __shared__ float sW[128 * 16];   // 8 KB
    __shared__ float sH[16 * 132];   // padded stride
    int tid = threadIdx.x;
    {
        const float4* W4 = (const float4*)Wc;
        float4* s4 = (float4*)sW;
        s4[tid] = W4[tid];
        s4[tid + 256] = W4[tid + 256];
    }
    int node0 = blockIdx.x * 16;
    for (int l = tid; l < 1024; l += 256) {
        int r = l >> 6, u = l & 63;
        int rr = node0 + r;
        int rc = rr < n ? rr : n - 1;
        uint v = Hb[(size_t)rc * 64 + u];
        sH[r * 132 + u * 2] = lo2f(v);
        sH[r * 132 + u * 2 + 1] = hi2f(v);
    }
    __syncthreads();

    int r = tid >> 4, c = tid & 15;
    float acc = 0.f;
#pragma unroll 4
    for (int k = 0; k < 128; ++k) acc = fmaf(sH[r * 132 + k], sW[k * 16 + c], acc);

    int rr = node0 + r;
    if (rr < n) out[(size_t)rr * 16 + c] = acc + bc[c];
}

// ---------------- launch ----------------

extern "C" void kernel_launch(void* const* d_in, const int* in_sizes, int n_in,
                              void* d_out, int out_size, void* d_ws, size_t ws_size,
                              hipStream_t stream) {
    const float* x  = (const float*)d_in[0];
    const int*   ei = (const int*)d_in[1];
    const float* W1 = (const float*)d_in[2];
    const float* b1 = (const float*)d_in[3];
    const float* W2 = (const float*)d_in[4];
    const float* b2 = (const float*)d_in[5];
    const float* Wc = (const float*)d_in[6];
    const float* bc = (const float*)d_in[7];
    float* out = (float*)d_out;

    const int n = in_sizes[0] / 128;  // 50000
    const int E = in_sizes[1] / 2;    // 1,600,000
    const int* src = ei;
    const int* dst = ei + E;
    const int nbuckets = (n + NPB - 1) / NPB;  // 196

    char* p = (char*)d_ws;
    auto alloc = [&](size_t bytes) {
        char* q = p;
        p += (bytes + 255) & ~(size_t)255;
        return q;
    };
    int*   bcount   = (int*)alloc(MAXBKT * 4);
    int*   bbase    = (int*)alloc((MAXBKT + 1) * 4);
    int*   bcursor  = (int*)alloc(MAXBKT * 4);
    int*   rowstart = (int*)alloc(((size_t)n + 1) * 4);
    int*   colidx   = (int*)alloc((size_t)E * 4);   // dead after edge_weights
    uint*  pay      = (uint*)alloc((size_t)E * 4);  // dead after build_rows
    ull*   pay2     = (ull*)alloc((size_t)E * 8);
    float* dinv     = (float*)alloc((size_t)n * 4);
    uint*  bufA     = (uint*)alloc((size_t)n * 64 * 4);  // bf16 h
    uint*  bufB     = (uint*)alloc((size_t)n * 64 * 4);
    uint*  bufC     = (uint*)colidx;  // reuse colidx+pay (12.8MB) for a2
    if ((size_t)(p - (char*)d_ws) > ws_size) return;

    hipMemsetAsync(bcount, 0, MAXBKT * 4, stream);

    const int eb = (E + 255) / 256;
    bucket_hist<<<256, 256, 0, stream>>>(dst, bcount, E, nbuckets);
    scan196<<<1, 256, 0, stream>>>(bcount, bbase, bcursor, nbuckets, E);
    bin_edges<<<256, 256, 0, stream>>>(src, dst, bcursor, pay, E, nbuckets);
    build_rows<<<nbuckets, 256, 0, stream>>>(pay, bbase, rowstart, dinv, colidx, n, E, nbuckets);
    edge_weights<<<eb, 256, 0, stream>>>(colidx, dinv, pay2, E);

    const int aggblocks = ((n + 3) / 4) * 4;  // 4 slices
    gemm128<false><<<(n + 63) / 64, 256, 0, stream>>>(x, W1, bufA, n);
    aggregate_slice<<<aggblocks, 256, 0, stream>>>(bufA, rowstart, pay2, dinv, b1, bufB, n);
    gemm128<true><<<(n + 63) / 64, 256, 0, stream>>>(bufB, W2, bufA, n);
    aggregate_slice<<<aggblocks, 256, 0, stream>>>(bufA, rowstart, pay2, dinv, b2, bufC, n);
    gemm_out16<<<(n + 15) / 16, 256, 0, stream>>>(bufC, Wc, bc, out, n);
}

// Round 8
// 301.765 us; speedup vs baseline: 1.5240x; 1.5240x over previous
//
#include <hip/hip_runtime.h>
#include <hip/hip_bf16.h>

// GCN on MI355X. Pipeline (7 launches):
//   initcur + bin_edges (fixed-cap buckets) + build_rows  : CSR by dst
//   gemm128<fp32>  : h1' = dinv ⊙ (x@W1)            -> bufA (bf16)
//   agg_mid_q      : a1 = relu(di*(self+Σ h1') + b1) -> bufB (bf16)
//   gemm128<bf16>  : h2' = dinv ⊙ (a1@W2)           -> bufA (bf16)
//   agg_out_q      : a2 = relu(di*(self+Σ h2') + b2); out = a2@Wc + bc
// Aggregate: one NODE per 16-lane quarter (4 nodes/wave): quarter gathers
// its node's edges 4-at-a-time unmasked (uint4/lane = 256B row), 1-edge
// tail. No per-edge weights (h pre-scaled by dinv in GEMM epilogue - GCN
// norm identity), no cross-lane reduce. 16 rows in flight/wave.
// h bf16; accumulation fp32. Requires n <= 65536.

typedef unsigned int uint;

#define NPB 256
#define MAXBKT 256
#define CAP 12288   // edges per bucket region; mean 8192, sd ~90 -> 45 sigma

static __device__ __forceinline__ unsigned short f2bf(float f) {
    unsigned u = __float_as_uint(f);
    u += 0x7fffu + ((u >> 16) & 1u);   // round-to-nearest-even
    return (unsigned short)(u >> 16);
}
static __device__ __forceinline__ uint pack2(float a, float b) {
    return (uint)f2bf(a) | ((uint)f2bf(b) << 16);
}
static __device__ __forceinline__ float lo2f(uint u) { return __uint_as_float(u << 16); }
static __device__ __forceinline__ float hi2f(uint u) { return __uint_as_float(u & 0xffff0000u); }

#define UNPACK8(dst, u)                                        \
    dst[0] = lo2f(u.x); dst[1] = hi2f(u.x);                    \
    dst[2] = lo2f(u.y); dst[3] = hi2f(u.y);                    \
    dst[4] = lo2f(u.z); dst[5] = hi2f(u.z);                    \
    dst[6] = lo2f(u.w); dst[7] = hi2f(u.w);

// ---------------- CSR build (fixed-capacity buckets) ----------------

__global__ __launch_bounds__(256) void initcur(int* __restrict__ bcursor, int nbuckets) {
    int t = threadIdx.x;
    if (t < nbuckets) bcursor[t] = t * CAP;
}

// coarse binning with fixed-stride bucket regions; payload = src|dstlocal<<24
__global__ __launch_bounds__(256) void bin_edges(const int* __restrict__ src,
                                                 const int* __restrict__ dst,
                                                 int* __restrict__ bcursor,
                                                 uint* __restrict__ pay,
                                                 int E, int nbuckets) {
    __shared__ int h[MAXBKT];
    __shared__ int base[MAXBKT];
    int tid = threadIdx.x;
    h[tid] = 0;
    __syncthreads();
    int chunk = (E + gridDim.x - 1) / gridDim.x;
    int i0 = blockIdx.x * chunk;
    int i1 = min(E, i0 + chunk);
    for (int i = i0 + tid; i < i1; i += 256) atomicAdd(&h[dst[i] >> 8], 1);
    __syncthreads();
    if (tid < nbuckets) base[tid] = h[tid] ? atomicAdd(&bcursor[tid], h[tid]) : 0;
    __syncthreads();
    h[tid] = 0;
    __syncthreads();
    for (int i = i0 + tid; i < i1; i += 256) {
        int d = dst[i];
        int b = d >> 8;
        int pos = base[b] + atomicAdd(&h[b], 1);
        pay[pos] = (uint)src[i] | ((uint)(d & 255) << 24);
    }
}

// per-bucket: degrees -> dinv/rowstart/rowend; dst-sorted colidx scatter
// (scatter stays inside one 48KB L2-resident region).
__global__ __launch_bounds__(256) void build_rows(const uint* __restrict__ pay,
                                                  const int* __restrict__ bcursor,
                                                  int* __restrict__ rowstart,
                                                  int* __restrict__ rowend,
                                                  float* __restrict__ dinv,
                                                  int* __restrict__ colidx, int n) {
    __shared__ int hist[NPB];
    __shared__ int sc[NPB];
    __shared__ int cur[NPB];
    int tid = threadIdx.x;
    int b = blockIdx.x;
    int node0 = b * NPB;
    int s = b * CAP, e = bcursor[b];

    hist[tid] = 0;
    __syncthreads();
    for (int i = s + tid; i < e; i += 256) atomicAdd(&hist[pay[i] >> 24], 1);
    __syncthreads();

    int v = hist[tid];
    sc[tid] = v;
    __syncthreads();
    for (int d = 1; d < 256; d <<= 1) {
        int x = (tid >= d) ? sc[tid - d] : 0;
        __syncthreads();
        sc[tid] += x;
        __syncthreads();
    }
    int excl = sc[tid] - v;
    cur[tid] = s + excl;
    int node = node0 + tid;
    if (node < n) {
        rowstart[node] = s + excl;
        rowend[node] = s + excl + v;
        dinv[node] = rsqrtf((float)(v + 1));  // +1 self-loop
    }
    __syncthreads();

    for (int i = s + tid; i < e; i += 256) {
        uint p = pay[i];
        int pos = atomicAdd(&cur[p >> 24], 1);
        colidx[pos] = (int)(p & 0xffffffu);
    }
}

// ------- GEMM n x 128 @ 128 x 128, x dinv[row], bf16 packed output -------
template <bool A_BF16>
__global__ __launch_bounds__(256) void gemm128(const void* __restrict__ Xv,
                                               const float* __restrict__ W,
                                               const float* __restrict__ dinv,
                                               uint* __restrict__ Yb, int n) {
    __shared__ float sW[32 * 128];  // 16 KB
    const int tid = threadIdx.x;
    const int row0 = blockIdx.x * 64;
    const int ty = tid >> 4, tx = tid & 15;
    const int c0 = tx * 4;
    int r[4];
#pragma unroll
    for (int i = 0; i < 4; ++i) {
        int rr = row0 + ty * 4 + i;
        r[i] = rr < n ? rr : n - 1;
    }

    float acc[4][8];
#pragma unroll
    for (int i = 0; i < 4; ++i)
#pragma unroll
        for (int j = 0; j < 8; ++j) acc[i][j] = 0.f;

    for (int kc = 0; kc < 128; kc += 32) {
        __syncthreads();
        {
            const float4* W4 = (const float4*)(W + kc * 128);
            float4* s4 = (float4*)sW;
#pragma unroll
            for (int i = 0; i < 4; ++i) s4[tid + 256 * i] = W4[tid + 256 * i];
        }
        __syncthreads();

        for (int k4 = 0; k4 < 32; k4 += 4) {
            float a[4][4];
            if (A_BF16) {
                const uint2* X2 = (const uint2*)Xv;
#pragma unroll
                for (int i = 0; i < 4; ++i) {
                    uint2 u = X2[(size_t)r[i] * 32 + ((kc + k4) >> 2)];
                    a[i][0] = lo2f(u.x); a[i][1] = hi2f(u.x);
                    a[i][2] = lo2f(u.y); a[i][3] = hi2f(u.y);
                }
            } else {
                const float4* X4 = (const float4*)Xv;
#pragma unroll
                for (int i = 0; i < 4; ++i) {
                    float4 vv = X4[(size_t)r[i] * 32 + ((kc + k4) >> 2)];
                    a[i][0] = vv.x; a[i][1] = vv.y; a[i][2] = vv.z; a[i][3] = vv.w;
                }
            }
#pragma unroll
            for (int kk = 0; kk < 4; ++kk) {
                const int k = k4 + kk;
                float4 w0 = *(const float4*)&sW[k * 128 + c0];
                float4 w1 = *(const float4*)&sW[k * 128 + 64 + c0];
                float wv[8] = {w0.x, w0.y, w0.z, w0.w, w1.x, w1.y, w1.z, w1.w};
#pragma unroll
                for (int i = 0; i < 4; ++i) {
                    float av = a[i][kk];
#pragma unroll
                    for (int j = 0; j < 8; ++j) acc[i][j] = fmaf(av, wv[j], acc[i][j]);
                }
            }
        }
    }

#pragma unroll
    for (int i = 0; i < 4; ++i) {
        int rr = row0 + ty * 4 + i;
        if (rr < n) {
            float di = dinv[rr];
            uint2 o0 = {pack2(di * acc[i][0], di * acc[i][1]),
                        pack2(di * acc[i][2], di * acc[i][3])};
            uint2 o1 = {pack2(di * acc[i][4], di * acc[i][5]),
                        pack2(di * acc[i][6], di * acc[i][7])};
            *(uint2*)&Yb[(size_t)rr * 64 + (c0 >> 1)] = o0;
            *(uint2*)&Yb[(size_t)rr * 64 + 32 + (c0 >> 1)] = o1;
        }
    }
}

// ---------------- aggregate core: one node per 16-lane quarter ----------------
// Quarter's 16 lanes: uint4/lane = the node's full 256B row. Unweighted sum
// (h pre-scaled). Unmasked 4-edge main loop + 1-edge tail. acc[8] complete
// per lane (cols sub*8..+8) - no cross-lane reduce.
static __device__ __forceinline__ void gather_q(const uint4* __restrict__ H4,
                                                int s, int e, int nn, int sub,
                                                const int* __restrict__ colidx,
                                                float acc[8]) {
    uint4 su = H4[(size_t)nn * 16 + sub];
    UNPACK8(acc, su);   // self term (h' already dinv-scaled)

    int p = s;
    for (; p + 4 <= e; p += 4) {
        int c0 = colidx[p], c1 = colidx[p + 1], c2 = colidx[p + 2], c3 = colidx[p + 3];
        uint4 u0 = H4[(size_t)c0 * 16 + sub];
        uint4 u1 = H4[(size_t)c1 * 16 + sub];
        uint4 u2 = H4[(size_t)c2 * 16 + sub];
        uint4 u3 = H4[(size_t)c3 * 16 + sub];
        float a0[8], a1[8], a2[8], a3[8];
        UNPACK8(a0, u0);
        UNPACK8(a1, u1);
        UNPACK8(a2, u2);
        UNPACK8(a3, u3);
#pragma unroll
        for (int j = 0; j < 8; ++j) acc[j] += (a0[j] + a1[j]) + (a2[j] + a3[j]);
    }
    for (; p < e; ++p) {
        int c = colidx[p];
        uint4 u = H4[(size_t)c * 16 + sub];
        float a[8];
        UNPACK8(a, u);
#pragma unroll
        for (int j = 0; j < 8; ++j) acc[j] += a[j];
    }
}

// middle layer: a1 = relu(di*sum + b1), bf16. 16 nodes/block.
__global__ __launch_bounds__(256) void agg_mid_q(const uint4* __restrict__ H4,
                                                 const int* __restrict__ rowstart,
                                                 const int* __restrict__ rowend,
                                                 const int* __restrict__ colidx,
                                                 const float* __restrict__ dinv,
                                                 const float* __restrict__ bias,
                                                 uint4* __restrict__ Ob, int n) {
    int tid = threadIdx.x;
    int sub = tid & 15;
    int node = blockIdx.x * 16 + (tid >> 4);
    int nn = node < n ? node : n - 1;
    int s = rowstart[nn], e = rowend[nn];
    float di = dinv[nn];

    float acc[8];
    gather_q(H4, s, e, nn, sub, colidx, acc);

    if (node < n) {
        float4 b0 = ((const float4*)bias)[sub * 2];
        float4 b1 = ((const float4*)bias)[sub * 2 + 1];
        float o0 = fmaxf(fmaf(acc[0], di, b0.x), 0.f);
        float o1 = fmaxf(fmaf(acc[1], di, b0.y), 0.f);
        float o2 = fmaxf(fmaf(acc[2], di, b0.z), 0.f);
        float o3 = fmaxf(fmaf(acc[3], di, b0.w), 0.f);
        float o4 = fmaxf(fmaf(acc[4], di, b1.x), 0.f);
        float o5 = fmaxf(fmaf(acc[5], di, b1.y), 0.f);
        float o6 = fmaxf(fmaf(acc[6], di, b1.z), 0.f);
        float o7 = fmaxf(fmaf(acc[7], di, b1.w), 0.f);
        uint4 ov;
        ov.x = pack2(o0, o1); ov.y = pack2(o2, o3);
        ov.z = pack2(o4, o5); ov.w = pack2(o6, o7);
        Ob[(size_t)node * 16 + sub] = ov;
    }
}

// final layer + classifier: a2 = relu(di*sum + b2) staged in LDS, then
// 256 threads = 16 nodes x 16 cols compute a2 @ Wc + bc.
__global__ __launch_bounds__(256) void agg_out_q(const uint4* __restrict__ H4,
                                                 const int* __restrict__ rowstart,
                                                 const int* __restrict__ rowend,
                                                 const int* __restrict__ colidx,
                                                 const float* __restrict__ dinv,
                                                 const float* __restrict__ bias,
                                                 const float* __restrict__ Wc,
                                                 const float* __restrict__ bc,
                                                 float* __restrict__ out, int n) {
    __shared__ float sA[16][129];  // bank (r+k)%32: groups hit distinct banks
    int tid = threadIdx.x;
    int sub = tid & 15;
    int nl = tid >> 4;             // node-local 0..15 (= wave*4 + quarter)
    int node = blockIdx.x * 16 + nl;
    int nn = node < n ? node : n - 1;
    int s = rowstart[nn], e = rowend[nn];
    float di = dinv[nn];

    float acc[8];
    gather_q(H4, s, e, nn, sub, colidx, acc);

    {
        float4 b0 = ((const float4*)bias)[sub * 2];
        float4 b1 = ((const float4*)bias)[sub * 2 + 1];
        float f[8];
        f[0] = fmaxf(fmaf(acc[0], di, b0.x), 0.f);
        f[1] = fmaxf(fmaf(acc[1], di, b0.y), 0.f);
        f[2] = fmaxf(fmaf(acc[2], di, b0.z), 0.f);
        f[3] = fmaxf(fmaf(acc[3], di, b0.w), 0.f);
        f[4] = fmaxf(fmaf(acc[4], di, b1.x), 0.f);
        f[5] = fmaxf(fmaf(acc[5], di, b1.y), 0.f);
        f[6] = fmaxf(fmaf(acc[6], di, b1.z), 0.f);
        f[7] = fmaxf(fmaf(acc[7], di, b1.w), 0.f);
#pragma unroll
        for (int j = 0; j < 8; ++j) sA[nl][sub * 8 + j] = f[j];
    }
    __syncthreads();

    // classifier: thread (nl, col). Wc row k is a 64B line, broadcast; L1-hot.
    int col = tid & 15;
    float p0 = 0.f, p1 = 0.f;
#pragma unroll 4
    for (int k = 0; k < 128; k += 2) {
        p0 = fmaf(sA[nl][k], Wc[k * 16 + col], p0);
        p1 = fmaf(sA[nl][k + 1], Wc[(k + 1) * 16 + col], p1);
    }
    if (node < n) out[(size_t)node * 16 + col] = p0 + p1 + bc[col];
}

// ---------------- launch ----------------

extern "C" void kernel_launch(void* const* d_in, const int* in_sizes, int n_in,
                              void* d_out, int out_size, void* d_ws, size_t ws_size,
                              hipStream_t stream) {
    const float* x  = (const float*)d_in[0];
    const int*   ei = (const int*)d_in[1];
    const float* W1 = (const float*)d_in[2];
    const float* b1 = (const float*)d_in[3];
    const float* W2 = (const float*)d_in[4];
    const float* b2 = (const float*)d_in[5];
    const float* Wc = (const float*)d_in[6];
    const float* bc = (const float*)d_in[7];
    float* out = (float*)d_out;

    const int n = in_sizes[0] / 128;  // 50000
    const int E = in_sizes[1] / 2;    // 1,600,000
    const int* src = ei;
    const int* dst = ei + E;
    const int nbuckets = (n + NPB - 1) / NPB;  // 196

    char* p = (char*)d_ws;
    auto alloc = [&](size_t bytes) {
        char* q = p;
        p += (bytes + 255) & ~(size_t)255;
        return q;
    };
    int*   bcursor  = (int*)alloc(MAXBKT * 4);
    int*   rowstart = (int*)alloc((size_t)n * 4);
    int*   rowend   = (int*)alloc((size_t)n * 4);
    float* dinv     = (float*)alloc((size_t)n * 4);
    uint*  pay      = (uint*)alloc((size_t)nbuckets * CAP * 4);
    int*   colidx   = (int*)alloc((size_t)nbuckets * CAP * 4);
    uint*  bufA     = (uint*)alloc((size_t)n * 64 * 4);  // bf16 h'
    uint*  bufB     = (uint*)alloc((size_t)n * 64 * 4);  // bf16 a1
    if ((size_t)(p - (char*)d_ws) > ws_size) return;

    initcur<<<1, 256, 0, stream>>>(bcursor, nbuckets);
    bin_edges<<<256, 256, 0, stream>>>(src, dst, bcursor, pay, E, nbuckets);
    build_rows<<<nbuckets, 256, 0, stream>>>(pay, bcursor, rowstart, rowend, dinv, colidx, n);

    const int gemmb = (n + 63) / 64;
    const int aggb = (n + 15) / 16;
    gemm128<false><<<gemmb, 256, 0, stream>>>(x, W1, dinv, bufA, n);
    agg_mid_q<<<aggb, 256, 0, stream>>>((const uint4*)bufA, rowstart, rowend, colidx,
                                        dinv, b1, (uint4*)bufB, n);
    gemm128<true><<<gemmb, 256, 0, stream>>>(bufB, W2, dinv, bufA, n);
    agg_out_q<<<aggb, 256, 0, stream>>>((const uint4*)bufA, rowstart, rowend, colidx,
                                        dinv, b2, Wc, bc, out, n);
}

// Round 9
// 284.820 us; speedup vs baseline: 1.6146x; 1.0595x over previous
//
#include <hip/hip_runtime.h>
#include <hip/hip_bf16.h>

// GCN on MI355X. Pipeline (8 launches):
//   initcur + bin_edges (fixed-cap buckets) + build_rows : CSR by dst
//   prep_wt        : W1,W2 -> bf16 transposed [n][k] (MFMA B-operand layout)
//   gemm_mfma<f32> : h1' = dinv ⊙ (x@W1)             -> bufA (bf16)
//   agg_mid_q      : a1 = relu(di*(self+Σ h1') + b1)  -> bufB (bf16)
//   gemm_mfma<bf16>: h2' = dinv ⊙ (a1@W2)            -> bufA (bf16)
//   agg_out_q      : a2 = relu(di*(self+Σ h2') + b2); out = a2@Wc + bc
// Aggregate: one NODE per 16-lane quarter (4/wave); unmasked 8-edge main
// loop (8 uint4 rows in flight = 2x R8 MLP), one masked-8 tail iteration
// (dummy = self row, compensated analytically). h pre-scaled by dinv in
// GEMM epilogue. GEMMs: mfma_f32_16x16x32_bf16, wave = 16 rows x 128 cols,
// B-frags from prep-transposed bf16 W^T (L1-resident), C via LDS bounce.
// h bf16; accumulation fp32. Requires n <= 65536.

typedef unsigned int uint;
typedef unsigned short ushort;
typedef __attribute__((ext_vector_type(8))) short bf16x8;
typedef __attribute__((ext_vector_type(4))) float f32x4;

#define NPB 256
#define MAXBKT 256
#define CAP 12288   // edges per bucket region; mean 8192, sd ~90

static __device__ __forceinline__ ushort f2bf(float f) {
    unsigned u = __float_as_uint(f);
    u += 0x7fffu + ((u >> 16) & 1u);   // round-to-nearest-even
    return (ushort)(u >> 16);
}
static __device__ __forceinline__ uint pack2(float a, float b) {
    return (uint)f2bf(a) | ((uint)f2bf(b) << 16);
}
static __device__ __forceinline__ float lo2f(uint u) { return __uint_as_float(u << 16); }
static __device__ __forceinline__ float hi2f(uint u) { return __uint_as_float(u & 0xffff0000u); }

#define UNPACK8(dst, u)                                        \
    dst[0] = lo2f(u.x); dst[1] = hi2f(u.x);                    \
    dst[2] = lo2f(u.y); dst[3] = hi2f(u.y);                    \
    dst[4] = lo2f(u.z); dst[5] = hi2f(u.z);                    \
    dst[6] = lo2f(u.w); dst[7] = hi2f(u.w);

// ---------------- CSR build (fixed-capacity buckets) ----------------

__global__ __launch_bounds__(256) void initcur(int* __restrict__ bcursor, int nbuckets) {
    int t = threadIdx.x;
    if (t < nbuckets) bcursor[t] = t * CAP;
}

__global__ __launch_bounds__(256) void bin_edges(const int* __restrict__ src,
                                                 const int* __restrict__ dst,
                                                 int* __restrict__ bcursor,
                                                 uint* __restrict__ pay,
                                                 int E, int nbuckets) {
    __shared__ int h[MAXBKT];
    __shared__ int base[MAXBKT];
    int tid = threadIdx.x;
    h[tid] = 0;
    __syncthreads();
    int chunk = (E + gridDim.x - 1) / gridDim.x;
    int i0 = blockIdx.x * chunk;
    int i1 = min(E, i0 + chunk);
    for (int i = i0 + tid; i < i1; i += 256) atomicAdd(&h[dst[i] >> 8], 1);
    __syncthreads();
    if (tid < nbuckets) base[tid] = h[tid] ? atomicAdd(&bcursor[tid], h[tid]) : 0;
    __syncthreads();
    h[tid] = 0;
    __syncthreads();
    for (int i = i0 + tid; i < i1; i += 256) {
        int d = dst[i];
        int b = d >> 8;
        int pos = base[b] + atomicAdd(&h[b], 1);
        pay[pos] = (uint)src[i] | ((uint)(d & 255) << 24);
    }
}

__global__ __launch_bounds__(256) void build_rows(const uint* __restrict__ pay,
                                                  const int* __restrict__ bcursor,
                                                  int* __restrict__ rowstart,
                                                  int* __restrict__ rowend,
                                                  float* __restrict__ dinv,
                                                  int* __restrict__ colidx, int n) {
    __shared__ int hist[NPB];
    __shared__ int sc[NPB];
    __shared__ int cur[NPB];
    int tid = threadIdx.x;
    int b = blockIdx.x;
    int node0 = b * NPB;
    int s = b * CAP, e = bcursor[b];

    hist[tid] = 0;
    __syncthreads();
    for (int i = s + tid; i < e; i += 256) atomicAdd(&hist[pay[i] >> 24], 1);
    __syncthreads();

    int v = hist[tid];
    sc[tid] = v;
    __syncthreads();
    for (int d = 1; d < 256; d <<= 1) {
        int x = (tid >= d) ? sc[tid - d] : 0;
        __syncthreads();
        sc[tid] += x;
        __syncthreads();
    }
    int excl = sc[tid] - v;
    cur[tid] = s + excl;
    int node = node0 + tid;
    if (node < n) {
        rowstart[node] = s + excl;
        rowend[node] = s + excl + v;
        dinv[node] = rsqrtf((float)(v + 1));  // +1 self-loop
    }
    __syncthreads();

    for (int i = s + tid; i < e; i += 256) {
        uint p = pay[i];
        int pos = atomicAdd(&cur[p >> 24], 1);
        colidx[pos] = (int)(p & 0xffffffu);
    }
}

// ---------------- W prep: bf16 transpose [n][k] for MFMA B-operand ----------
__global__ __launch_bounds__(256) void prep_wt(const float* __restrict__ W1,
                                               const float* __restrict__ W2,
                                               ushort* __restrict__ Wt1,
                                               ushort* __restrict__ Wt2) {
    int idx = blockIdx.x * 256 + threadIdx.x;  // 0..16383
    int k = idx >> 7, nn = idx & 127;
    Wt1[nn * 128 + k] = f2bf(W1[idx]);
    Wt2[nn * 128 + k] = f2bf(W2[idx]);
}

// ------- MFMA GEMM: Y[n x 128] = dinv ⊙ (X @ W), bf16 packed output -------
// Block 256 = 4 waves; wave computes 16 rows x 128 cols.
// mfma_f32_16x16x32_bf16 layouts (verified learn_hip m89/m120):
//   A[m][k]: m=lane&15, k=quad*8+j    B[k][n]: n=lane&15, k=quad*8+j
//   C/D:     col=lane&15, row=quad*4+reg
// B read from Wt[n][k] (transposed) -> 16B contiguous per lane, L1-resident.
template <bool A_BF16>
__global__ __launch_bounds__(256) void gemm_mfma(const void* __restrict__ Xv,
                                                 const ushort* __restrict__ Wt,
                                                 const float* __restrict__ dinv,
                                                 uint* __restrict__ Yb, int n) {
    __shared__ __align__(16) ushort sOut[4][16][136];  // pad: 272B row stride
    const int wave = threadIdx.x >> 6;
    const int lane = threadIdx.x & 63;
    const int quad = lane >> 4, l16 = lane & 15;
    const int m0 = blockIdx.x * 64 + wave * 16;

    f32x4 acc[8];
#pragma unroll
    for (int t = 0; t < 8; ++t) acc[t] = (f32x4){0.f, 0.f, 0.f, 0.f};

    int arow = m0 + l16;
    arow = arow < n ? arow : n - 1;

#pragma unroll
    for (int ks = 0; ks < 4; ++ks) {
        bf16x8 a;
        if (A_BF16) {
            const ushort* X = (const ushort*)Xv;
            a = *(const bf16x8*)&X[(size_t)arow * 128 + ks * 32 + quad * 8];
        } else {
            const float* X = (const float*)Xv;
            const float* px = &X[(size_t)arow * 128 + ks * 32 + quad * 8];
            float4 x0 = *(const float4*)px;
            float4 x1 = *(const float4*)(px + 4);
            ushort av[8] = {f2bf(x0.x), f2bf(x0.y), f2bf(x0.z), f2bf(x0.w),
                            f2bf(x1.x), f2bf(x1.y), f2bf(x1.z), f2bf(x1.w)};
            a = *(const bf16x8*)av;
        }
#pragma unroll
        for (int nt = 0; nt < 8; ++nt) {
            bf16x8 b = *(const bf16x8*)&Wt[(size_t)(nt * 16 + l16) * 128 + ks * 32 + quad * 8];
            acc[nt] = __builtin_amdgcn_mfma_f32_16x16x32_bf16(a, b, acc[nt], 0, 0, 0);
        }
    }

    // epilogue: scale rows by dinv, pack bf16 into LDS, coalesced store
    float dv[4];
#pragma unroll
    for (int r = 0; r < 4; ++r) {
        int rr = m0 + quad * 4 + r;
        dv[r] = dinv[rr < n ? rr : n - 1];
    }
#pragma unroll
    for (int nt = 0; nt < 8; ++nt)
#pragma unroll
        for (int r = 0; r < 4; ++r)
            sOut[wave][quad * 4 + r][nt * 16 + l16] = f2bf(acc[nt][r] * dv[r]);
    __syncthreads();

#pragma unroll
    for (int i = 0; i < 4; ++i) {
        int linear = i * 64 + lane;
        int row = linear >> 4, chunk = linear & 15;
        int rr = m0 + row;
        if (rr < n) {
            uint4 v = *(const uint4*)&sOut[wave][row][chunk * 8];
            *(uint4*)&Yb[(size_t)rr * 64 + chunk * 4] = v;
        }
    }
}

// ---------------- aggregate core: one node per 16-lane quarter ----------------
// Unmasked 8-edge main loop (8 rows in flight), one masked-8 tail iteration
// with dummy = self row (L1-hot) compensated by acc -= pad * t.
static __device__ __forceinline__ void gather_q(const uint4* __restrict__ H4,
                                                int s, int e, int nn, int sub,
                                                const int* __restrict__ colidx,
                                                float acc[8]) {
    uint4 su = H4[(size_t)nn * 16 + sub];
    float t[8];
    UNPACK8(t, su);
#pragma unroll
    for (int j = 0; j < 8; ++j) acc[j] = t[j];   // self term (pre-scaled h')

    int p = s;
    for (; p + 8 <= e; p += 8) {
        int c[8];
#pragma unroll
        for (int i = 0; i < 8; ++i) c[i] = colidx[p + i];
        uint4 u[8];
#pragma unroll
        for (int i = 0; i < 8; ++i) u[i] = H4[(size_t)c[i] * 16 + sub];
#pragma unroll
        for (int i = 0; i < 8; ++i) {
            float a[8];
            UNPACK8(a, u[i]);
#pragma unroll
            for (int j = 0; j < 8; ++j) acc[j] += a[j];
        }
    }
    if (p < e) {
        int c[8];
#pragma unroll
        for (int i = 0; i < 8; ++i) c[i] = (p + i < e) ? colidx[p + i] : nn;
        uint4 u[8];
#pragma unroll
        for (int i = 0; i < 8; ++i) u[i] = H4[(size_t)c[i] * 16 + sub];
#pragma unroll
        for (int i = 0; i < 8; ++i) {
            float a[8];
            UNPACK8(a, u[i]);
#pragma unroll
            for (int j = 0; j < 8; ++j) acc[j] += a[j];
        }
        float pad = (float)(p + 8 - e);   // dummies added self row 'pad' times
#pragma unroll
        for (int j = 0; j < 8; ++j) acc[j] -= pad * t[j];
    }
}

// middle layer: a1 = relu(di*sum + b1), bf16. 16 nodes/block.
__global__ __launch_bounds__(256) void agg_mid_q(const uint4* __restrict__ H4,
                                                 const int* __restrict__ rowstart,
                                                 const int* __restrict__ rowend,
                                                 const int* __restrict__ colidx,
                                                 const float* __restrict__ dinv,
                                                 const float* __restrict__ bias,
                                                 uint4* __restrict__ Ob, int n) {
    int tid = threadIdx.x;
    int sub = tid & 15;
    int node = blockIdx.x * 16 + (tid >> 4);
    int nn = node < n ? node : n - 1;
    int s = rowstart[nn], e = rowend[nn];
    float di = dinv[nn];

    float acc[8];
    gather_q(H4, s, e, nn, sub, colidx, acc);

    if (node < n) {
        float4 b0 = ((const float4*)bias)[sub * 2];
        float4 b1 = ((const float4*)bias)[sub * 2 + 1];
        float o0 = fmaxf(fmaf(acc[0], di, b0.x), 0.f);
        float o1 = fmaxf(fmaf(acc[1], di, b0.y), 0.f);
        float o2 = fmaxf(fmaf(acc[2], di, b0.z), 0.f);
        float o3 = fmaxf(fmaf(acc[3], di, b0.w), 0.f);
        float o4 = fmaxf(fmaf(acc[4], di, b1.x), 0.f);
        float o5 = fmaxf(fmaf(acc[5], di, b1.y), 0.f);
        float o6 = fmaxf(fmaf(acc[6], di, b1.z), 0.f);
        float o7 = fmaxf(fmaf(acc[7], di, b1.w), 0.f);
        uint4 ov;
        ov.x = pack2(o0, o1); ov.y = pack2(o2, o3);
        ov.z = pack2(o4, o5); ov.w = pack2(o6, o7);
        Ob[(size_t)node * 16 + sub] = ov;
    }
}

// final layer + classifier: a2 staged in LDS, 256 thr = 16 nodes x 16 cols.
__global__ __launch_bounds__(256) void agg_out_q(const uint4* __restrict__ H4,
                                                 const int* __restrict__ rowstart,
                                                 const int* __restrict__ rowend,
                                                 const int* __restrict__ colidx,
                                                 const float* __restrict__ dinv,
                                                 const float* __restrict__ bias,
                                                 const float* __restrict__ Wc,
                                                 const float* __restrict__ bc,
                                                 float* __restrict__ out, int n) {
    __shared__ float sA[16][129];
    int tid = threadIdx.x;
    int sub = tid & 15;
    int nl = tid >> 4;
    int node = blockIdx.x * 16 + nl;
    int nn = node < n ? node : n - 1;
    int s = rowstart[nn], e = rowend[nn];
    float di = dinv[nn];

    float acc[8];
    gather_q(H4, s, e, nn, sub, colidx, acc);

    {
        float4 b0 = ((const float4*)bias)[sub * 2];
        float4 b1 = ((const float4*)bias)[sub * 2 + 1];
        float f[8];
        f[0] = fmaxf(fmaf(acc[0], di, b0.x), 0.f);
        f[1] = fmaxf(fmaf(acc[1], di, b0.y), 0.f);
        f[2] = fmaxf(fmaf(acc[2], di, b0.z), 0.f);
        f[3] = fmaxf(fmaf(acc[3], di, b0.w), 0.f);
        f[4] = fmaxf(fmaf(acc[4], di, b1.x), 0.f);
        f[5] = fmaxf(fmaf(acc[5], di, b1.y), 0.f);
        f[6] = fmaxf(fmaf(acc[6], di, b1.z), 0.f);
        f[7] = fmaxf(fmaf(acc[7], di, b1.w), 0.f);
#pragma unroll
        for (int j = 0; j < 8; ++j) sA[nl][sub * 8 + j] = f[j];
    }
    __syncthreads();

    int col = tid & 15;
    float p0 = 0.f, p1 = 0.f;
#pragma unroll 4
    for (int k = 0; k < 128; k += 2) {
        p0 = fmaf(sA[nl][k], Wc[k * 16 + col], p0);
        p1 = fmaf(sA[nl][k + 1], Wc[(k + 1) * 16 + col], p1);
    }
    if (node < n) out[(size_t)node * 16 + col] = p0 + p1 + bc[col];
}

// ---------------- launch ----------------

extern "C" void kernel_launch(void* const* d_in, const int* in_sizes, int n_in,
                              void* d_out, int out_size, void* d_ws, size_t ws_size,
                              hipStream_t stream) {
    const float* x  = (const float*)d_in[0];
    const int*   ei = (const int*)d_in[1];
    const float* W1 = (const float*)d_in[2];
    const float* b1 = (const float*)d_in[3];
    const float* W2 = (const float*)d_in[4];
    const float* b2 = (const float*)d_in[5];
    const float* Wc = (const float*)d_in[6];
    const float* bc = (const float*)d_in[7];
    float* out = (float*)d_out;

    const int n = in_sizes[0] / 128;  // 50000
    const int E = in_sizes[1] / 2;    // 1,600,000
    const int* src = ei;
    const int* dst = ei + E;
    const int nbuckets = (n + NPB - 1) / NPB;  // 196

    char* p = (char*)d_ws;
    auto alloc = [&](size_t bytes) {
        char* q = p;
        p += (bytes + 255) & ~(size_t)255;
        return q;
    };
    int*    bcursor  = (int*)alloc(MAXBKT * 4);
    int*    rowstart = (int*)alloc((size_t)n * 4);
    int*    rowend   = (int*)alloc((size_t)n * 4);
    float*  dinv     = (float*)alloc((size_t)n * 4);
    ushort* Wt1      = (ushort*)alloc(128 * 128 * 2);
    ushort* Wt2      = (ushort*)alloc(128 * 128 * 2);
    uint*   pay      = (uint*)alloc((size_t)nbuckets * CAP * 4);
    int*    colidx   = (int*)alloc((size_t)nbuckets * CAP * 4);
    uint*   bufA     = (uint*)alloc((size_t)n * 64 * 4);  // bf16 h'
    uint*   bufB     = (uint*)alloc((size_t)n * 64 * 4);  // bf16 a1
    if ((size_t)(p - (char*)d_ws) > ws_size) return;

    initcur<<<1, 256, 0, stream>>>(bcursor, nbuckets);
    bin_edges<<<256, 256, 0, stream>>>(src, dst, bcursor, pay, E, nbuckets);
    build_rows<<<nbuckets, 256, 0, stream>>>(pay, bcursor, rowstart, rowend, dinv, colidx, n);
    prep_wt<<<64, 256, 0, stream>>>(W1, W2, Wt1, Wt2);

    const int gemmb = (n + 63) / 64;
    const int aggb = (n + 15) / 16;
    gemm_mfma<false><<<gemmb, 256, 0, stream>>>(x, Wt1, dinv, bufA, n);
    agg_mid_q<<<aggb, 256, 0, stream>>>((const uint4*)bufA, rowstart, rowend, colidx,
                                        dinv, b1, (uint4*)bufB, n);
    gemm_mfma<true><<<gemmb, 256, 0, stream>>>(bufB, Wt2, dinv, bufA, n);
    agg_out_q<<<aggb, 256, 0, stream>>>((const uint4*)bufA, rowstart, rowend, colidx,
                                        dinv, b2, Wc, bc, out, n);
}